// Round 1
// baseline (863.525 us; speedup 1.0000x reference)
//
#include <hip/hip_runtime.h>
#include <math.h>

#define BS 32
#define N 2048
#define ROWS (BS * N)
#define IN 128
#define HID 64
#define K_CAP 80
#define EPS 1e-5f
#define ALPHA 0.1f

// ---------------------------------------------------------------------------
// Kernel 1: build ELL adjacency + dinv = rsqrt(deg+1).
// One wave (64 lanes) per row; ballot-compact nonzero columns.
// Reads adj (536 MB) exactly once -> this is the HBM floor of the problem.
// ---------------------------------------------------------------------------
__global__ __launch_bounds__(256) void k_build(const float* __restrict__ adj,
                                               int* __restrict__ ell,
                                               int* __restrict__ cnt,
                                               float* __restrict__ dinv) {
    int lane = threadIdx.x & 63;
    int row  = blockIdx.x * 4 + (threadIdx.x >> 6);
    const float* arow = adj + (size_t)row * N;
    int* erow = ell + (size_t)row * K_CAP;
    int base = 0;
    for (int t = 0; t < N; t += 64) {
        float v = arow[t + lane];
        unsigned long long m = __ballot(v != 0.0f);
        if (v != 0.0f) {
            int pos = base + __popcll(m & ((1ull << lane) - 1ull));
            if (pos < K_CAP) erow[pos] = t + lane;  // local column index
        }
        base += __popcll(m);
    }
    if (lane == 0) {
        cnt[row]  = base < K_CAP ? base : K_CAP;
        dinv[row] = rsqrtf((float)base + 1.0f);  // self-loop adds 1 to degree
    }
}

// ---------------------------------------------------------------------------
// Kernel 2: h = x @ proj_w + proj_b.   [65536,128] @ [128,64]
// Block = 256 threads = 4 rows x 64 cols; W staged in LDS (32 KB).
// ---------------------------------------------------------------------------
__global__ __launch_bounds__(256) void k_proj(const float* __restrict__ x,
                                              const float* __restrict__ w,
                                              const float* __restrict__ b,
                                              float* __restrict__ h) {
    __shared__ float sw[IN * HID];
    __shared__ float sx[4][IN];
    int tx = threadIdx.x;
    for (int i = tx; i < IN * HID; i += 256) sw[i] = w[i];
    int row0 = blockIdx.x * 4;
    for (int i = tx; i < 4 * IN; i += 256)
        sx[i >> 7][i & 127] = x[(size_t)(row0 + (i >> 7)) * IN + (i & 127)];
    __syncthreads();
    int c = tx & 63, r = tx >> 6;
    float acc = b[c];
#pragma unroll
    for (int k = 0; k < IN; k++) acc += sx[r][k] * sw[k * HID + c];
    h[(size_t)(row0 + r) * HID + c] = acc;
}

// ---------------------------------------------------------------------------
// Kernel 3: z = relu(layer_norm(h, g, b)).  Wave per row, lane = feature.
// ---------------------------------------------------------------------------
__global__ __launch_bounds__(256) void k_ln(const float* __restrict__ h,
                                            const float* __restrict__ g,
                                            const float* __restrict__ b,
                                            float* __restrict__ z) {
    int lane = threadIdx.x & 63;
    int row  = blockIdx.x * 4 + (threadIdx.x >> 6);
    float v = h[(size_t)row * HID + lane];
    float sum = v;
    for (int off = 32; off >= 1; off >>= 1) sum += __shfl_xor(sum, off);
    float mu = sum * (1.0f / 64.0f);
    float d  = v - mu;
    float vs = d * d;
    for (int off = 32; off >= 1; off >>= 1) vs += __shfl_xor(vs, off);
    float r  = rsqrtf(vs * (1.0f / 64.0f) + EPS);
    float zz = d * r * g[lane] + b[lane];
    z[(size_t)row * HID + lane] = zz > 0.0f ? zz : 0.0f;
}

// ---------------------------------------------------------------------------
// Kernel 4: s = (1-ALPHA) * (A_hat @ z) + ALPHA * z.   Wave per row.
// p_row = dinv[i] * ( sum_{j in N(i)} dinv[j]*z[j] + dinv[i]*z[i] )
// Neighbor z rows live in the same batch slab (512 KB) -> L2-served.
// ---------------------------------------------------------------------------
__global__ __launch_bounds__(256) void k_spmm(const float* __restrict__ z,
                                              const int* __restrict__ ell,
                                              const int* __restrict__ cnt,
                                              const float* __restrict__ dinv,
                                              float* __restrict__ s) {
    int lane = threadIdx.x & 63;
    int row  = blockIdx.x * 4 + (threadIdx.x >> 6);
    int jbase = row & ~(N - 1);  // batch base row (N is a power of 2)
    const int* erow = ell + (size_t)row * K_CAP;
    int n = cnt[row];
    float di = dinv[row];
    float zi = z[(size_t)row * HID + lane];
    float acc = di * zi;  // self loop
    for (int t = 0; t < n; t++) {
        int j = jbase + erow[t];
        acc += dinv[j] * z[(size_t)j * HID + lane];
    }
    s[(size_t)row * HID + lane] = (1.0f - ALPHA) * di * acc + ALPHA * zi;
}

// ---------------------------------------------------------------------------
// Kernel 5: h = h + (1-beta)*s + beta*(s @ conv_w).  [65536,64] @ [64,64]
// Block = 4 rows x 64 cols; conv_w (16 KB) + 4 s-rows staged in LDS.
// ---------------------------------------------------------------------------
__global__ __launch_bounds__(256) void k_update(float* __restrict__ h,
                                                const float* __restrict__ s,
                                                const float* __restrict__ w,
                                                float beta) {
    __shared__ float sw[HID * HID];
    __shared__ float ss[4][HID];
    int tx = threadIdx.x;
    for (int i = tx; i < HID * HID; i += 256) sw[i] = w[i];
    int row0 = blockIdx.x * 4;
    int c = tx & 63, r = tx >> 6;
    ss[r][c] = s[(size_t)(row0 + r) * HID + c];
    __syncthreads();
    float acc = 0.0f;
#pragma unroll
    for (int k = 0; k < HID; k++) acc += ss[r][k] * sw[k * HID + c];
    size_t idx = (size_t)(row0 + r) * HID + c;
    h[idx] = h[idx] + (1.0f - beta) * ss[r][c] + beta * acc;
}

// ---------------------------------------------------------------------------
// Kernel 6: out = h @ head_w + head_b.  Wave per row, shuffle reduce.
// ---------------------------------------------------------------------------
__global__ __launch_bounds__(256) void k_head(const float* __restrict__ h,
                                              const float* __restrict__ w,
                                              const float* __restrict__ b,
                                              float* __restrict__ out) {
    int lane = threadIdx.x & 63;
    int row  = blockIdx.x * 4 + (threadIdx.x >> 6);
    float v = h[(size_t)row * HID + lane] * w[lane];
    for (int off = 32; off >= 1; off >>= 1) v += __shfl_xor(v, off);
    if (lane == 0) out[row] = v + b[0];
}

extern "C" void kernel_launch(void* const* d_in, const int* in_sizes, int n_in,
                              void* d_out, int out_size, void* d_ws, size_t ws_size,
                              hipStream_t stream) {
    const float* x      = (const float*)d_in[0];
    const float* adj    = (const float*)d_in[1];
    const float* proj_w = (const float*)d_in[2];
    const float* proj_b = (const float*)d_in[3];
    const float* ln_g   = (const float*)d_in[4];
    const float* ln_b   = (const float*)d_in[5];
    const float* conv_w = (const float*)d_in[6];
    const float* head_w = (const float*)d_in[7];
    const float* head_b = (const float*)d_in[8];
    float* out = (float*)d_out;

    // Workspace layout (~72 MB total)
    float* h    = (float*)d_ws;                 // ROWS*HID
    float* z    = h + (size_t)ROWS * HID;       // ROWS*HID
    float* s    = z + (size_t)ROWS * HID;       // ROWS*HID
    float* dinv = s + (size_t)ROWS * HID;       // ROWS
    int*   cnt  = (int*)(dinv + ROWS);          // ROWS
    int*   ell  = cnt + ROWS;                   // ROWS*K_CAP

    dim3 blk(256);
    dim3 grd(ROWS / 4);

    k_build<<<grd, blk, 0, stream>>>(adj, ell, cnt, dinv);
    k_proj<<<grd, blk, 0, stream>>>(x, proj_w, proj_b, h);

    for (int i = 0; i < 4; i++) {
        float beta = (float)log(1.0 / (double)(i + 1) + 1.0);  // GCNII beta
        k_ln<<<grd, blk, 0, stream>>>(h, ln_g + i * HID, ln_b + i * HID, z);
        k_spmm<<<grd, blk, 0, stream>>>(z, ell, cnt, dinv, s);
        k_update<<<grd, blk, 0, stream>>>(h, s, conv_w + (size_t)i * HID * HID, beta);
    }

    k_head<<<grd, blk, 0, stream>>>(h, head_w, head_b, out);
}

// Round 2
// 614.103 us; speedup vs baseline: 1.4062x; 1.4062x over previous
//
#include <hip/hip_runtime.h>
#include <math.h>

#define BS 32
#define N 2048
#define ROWS (BS * N)
#define IN 128
#define HID 64
#define K_CAP 80
#define EPS 1e-5f
#define ALPHA 0.1f

// ---------------------------------------------------------------------------
// Kernel 1: build ELL adjacency + dinv = rsqrt(deg+1).
// One wave per row; float4 loads (8 per row) + ballot-compaction.
// Reads adj (536 MB) exactly once -> the HBM floor of the whole problem.
// Neighbor ORDER is irrelevant (the aggregation is a sum), so the
// interleaved column order from float4 lanes is fine.
// ---------------------------------------------------------------------------
__global__ __launch_bounds__(256) void k_build(const float* __restrict__ adj,
                                               int* __restrict__ ell,
                                               int* __restrict__ cnt,
                                               float* __restrict__ dinv) {
    int lane = threadIdx.x & 63;
    int row  = blockIdx.x * 4 + (threadIdx.x >> 6);
    const float4* arow = (const float4*)(adj + (size_t)row * N);
    int* erow = ell + (size_t)row * K_CAP;
    int base = 0;
#pragma unroll
    for (int it = 0; it < N / 256; it++) {
        float4 f = arow[it * 64 + lane];
#pragma unroll
        for (int k = 0; k < 4; k++) {
            float v = (&f.x)[k];
            unsigned long long m = __ballot(v != 0.0f);
            if (v != 0.0f) {
                int pos = base + __popcll(m & ((1ull << lane) - 1ull));
                if (pos < K_CAP) erow[pos] = it * 256 + lane * 4 + k;
            }
            base += __popcll(m);
        }
    }
    if (lane == 0) {
        cnt[row]  = base < K_CAP ? base : K_CAP;
        dinv[row] = rsqrtf((float)base + 1.0f);  // self-loop adds 1
    }
}

// ---------------------------------------------------------------------------
// Kernel 2: h = x @ proj_w + proj_b, fused with layer-0 LN+ReLU -> z0.
// Block = 256 = 4 rows x 64 cols (one wave per row). W staged in LDS.
// ---------------------------------------------------------------------------
__global__ __launch_bounds__(256) void k_proj_ln(const float* __restrict__ x,
                                                 const float* __restrict__ w,
                                                 const float* __restrict__ b,
                                                 const float* __restrict__ g0,
                                                 const float* __restrict__ b0,
                                                 float* __restrict__ h,
                                                 float* __restrict__ z0) {
    __shared__ float sw[IN * HID];
    __shared__ float sx[4][IN];
    int tx = threadIdx.x;
    for (int i = tx; i < IN * HID; i += 256) sw[i] = w[i];
    int row0 = blockIdx.x * 4;
    for (int i = tx; i < 4 * IN; i += 256)
        sx[i >> 7][i & 127] = x[(size_t)(row0 + (i >> 7)) * IN + (i & 127)];
    __syncthreads();
    int c = tx & 63, r = tx >> 6;
    float acc = b[c];
#pragma unroll
    for (int k = 0; k < IN; k++) acc += sx[r][k] * sw[k * HID + c];
    size_t idx = (size_t)(row0 + r) * HID + c;
    h[idx] = acc;
    // LN + ReLU across the wave (lane = feature)
    float sum = acc;
    for (int o = 32; o >= 1; o >>= 1) sum += __shfl_xor(sum, o);
    float mu = sum * (1.0f / 64.0f);
    float d  = acc - mu;
    float vs = d * d;
    for (int o = 32; o >= 1; o >>= 1) vs += __shfl_xor(vs, o);
    float rr = rsqrtf(vs * (1.0f / 64.0f) + EPS);
    float zz = d * rr * g0[c] + b0[c];
    z0[idx] = zz > 0.0f ? zz : 0.0f;
}

// ---------------------------------------------------------------------------
// Kernel 3 (per layer, fully fused):
//   s   = (1-ALPHA) * (A_hat @ z_in) + ALPHA * z_in        (wave gather)
//   h  += (1-beta)*s + beta*(s @ conv_w)                   (LDS matvec)
//   z_out = relu(LN(h, g_next, b_next))   OR   out = h @ head_w + head_b
// Block = 256 = 4 rows x 64 cols. conv_w (16 KB) + s rows (1 KB) in LDS.
// Neighbor indices/weights preloaded per-lane, broadcast via __shfl, so the
// gather loop has no memory-dependent address chain.
// ---------------------------------------------------------------------------
__global__ __launch_bounds__(256) void k_layer(
    float* __restrict__ h, const float* __restrict__ z_in,
    float* __restrict__ z_out,
    const int* __restrict__ ell, const int* __restrict__ cnt,
    const float* __restrict__ dinv, const float* __restrict__ w,
    const float* __restrict__ g_next, const float* __restrict__ b_next,
    float beta, int is_last,
    const float* __restrict__ head_w, const float* __restrict__ head_b,
    float* __restrict__ out) {
    __shared__ float sw[HID * HID];
    __shared__ float ss[4][HID];
    int tx = threadIdx.x;
    int lane = tx & 63, r = tx >> 6;
    int row = blockIdx.x * 4 + r;
    for (int i = tx; i < HID * HID; i += 256) sw[i] = w[i];

    int jbase = row & ~(N - 1);  // batch slab base
    const int* erow = ell + (size_t)row * K_CAP;
    int n = cnt[row];
    float di = dinv[row];
    float zi = z_in[(size_t)row * HID + lane];
    int   myidx = 0;
    float myw   = 0.0f;
    if (lane < n) { myidx = erow[lane]; myw = dinv[jbase + myidx]; }
    float acc = di * zi;  // self loop
    int nmain = n < 64 ? n : 64;
    for (int t = 0; t < nmain; t++) {
        int   j  = jbase + __shfl(myidx, t);
        float wj = __shfl(myw, t);
        acc += wj * z_in[(size_t)j * HID + lane];
    }
    for (int t = 64; t < n; t++) {  // rare tail (deg > 64)
        int j = jbase + erow[t];
        acc += dinv[j] * z_in[(size_t)j * HID + lane];
    }
    float s = (1.0f - ALPHA) * di * acc + ALPHA * zi;
    ss[r][lane] = s;
    __syncthreads();
    float mv = 0.0f;
#pragma unroll
    for (int k = 0; k < HID; k++) mv += ss[r][k] * sw[k * HID + lane];
    size_t idx = (size_t)row * HID + lane;
    float hn = h[idx] + (1.0f - beta) * s + beta * mv;
    if (!is_last) {
        h[idx] = hn;
        float sum = hn;
        for (int o = 32; o >= 1; o >>= 1) sum += __shfl_xor(sum, o);
        float mu = sum * (1.0f / 64.0f);
        float d  = hn - mu;
        float vs = d * d;
        for (int o = 32; o >= 1; o >>= 1) vs += __shfl_xor(vs, o);
        float rr = rsqrtf(vs * (1.0f / 64.0f) + EPS);
        float zz = d * rr * g_next[lane] + b_next[lane];
        z_out[idx] = zz > 0.0f ? zz : 0.0f;
    } else {
        float v = hn * head_w[lane];
        for (int o = 32; o >= 1; o >>= 1) v += __shfl_xor(v, o);
        if (lane == 0) out[row] = v + head_b[0];
    }
}

extern "C" void kernel_launch(void* const* d_in, const int* in_sizes, int n_in,
                              void* d_out, int out_size, void* d_ws, size_t ws_size,
                              hipStream_t stream) {
    const float* x      = (const float*)d_in[0];
    const float* adj    = (const float*)d_in[1];
    const float* proj_w = (const float*)d_in[2];
    const float* proj_b = (const float*)d_in[3];
    const float* ln_g   = (const float*)d_in[4];
    const float* ln_b   = (const float*)d_in[5];
    const float* conv_w = (const float*)d_in[6];
    const float* head_w = (const float*)d_in[7];
    const float* head_b = (const float*)d_in[8];
    float* out = (float*)d_out;

    // Workspace layout (~53 MB)
    float* h    = (float*)d_ws;                  // ROWS*HID
    float* za   = h + (size_t)ROWS * HID;        // ROWS*HID
    float* zb   = za + (size_t)ROWS * HID;       // ROWS*HID
    float* dinv = zb + (size_t)ROWS * HID;       // ROWS
    int*   cnt  = (int*)(dinv + ROWS);           // ROWS
    int*   ell  = cnt + ROWS;                    // ROWS*K_CAP

    dim3 blk(256), grd(ROWS / 4);

    k_build<<<grd, blk, 0, stream>>>(adj, ell, cnt, dinv);
    k_proj_ln<<<grd, blk, 0, stream>>>(x, proj_w, proj_b, ln_g, ln_b, h, za);

    float* zin = za;
    float* zout = zb;
    for (int i = 0; i < 4; i++) {
        float beta = (float)log(1.0 / (double)(i + 1) + 1.0);
        int last = (i == 3);
        int gi = (i + 1) < 3 ? (i + 1) : 3;  // keep pointer in-bounds; unused when last
        k_layer<<<grd, blk, 0, stream>>>(h, zin, zout, ell, cnt, dinv,
                                         conv_w + (size_t)i * HID * HID,
                                         ln_g + gi * HID, ln_b + gi * HID,
                                         beta, last, head_w, head_b, out);
        float* t = zin; zin = zout; zout = t;
    }
}

// Round 4
// 459.365 us; speedup vs baseline: 1.8798x; 1.3369x over previous
//
#include <hip/hip_runtime.h>
#include <math.h>

#define BS 32
#define N 2048
#define ROWS (BS * N)
#define IN 128
#define HID 64
#define K_CAP 80
#define EPS 1e-5f
#define ALPHA 0.1f

// ---------------------------------------------------------------------------
// Kernel 1: build ELL adjacency + dinv = rsqrt(deg+1).
// One wave per row; float4 loads (8 per row) + ballot-compaction.
// Reads adj (536 MB) exactly once -> the HBM floor of the whole problem.
// ---------------------------------------------------------------------------
__global__ __launch_bounds__(256) void k_build(const float* __restrict__ adj,
                                               int* __restrict__ ell,
                                               int* __restrict__ cnt,
                                               float* __restrict__ dinv) {
    int lane = threadIdx.x & 63;
    int row  = blockIdx.x * 4 + (threadIdx.x >> 6);
    const float4* arow = (const float4*)(adj + (size_t)row * N);
    int* erow = ell + (size_t)row * K_CAP;
    int base = 0;
#pragma unroll
    for (int it = 0; it < N / 256; it++) {
        float4 f = arow[it * 64 + lane];
#pragma unroll
        for (int k = 0; k < 4; k++) {
            float v = (&f.x)[k];
            unsigned long long m = __ballot(v != 0.0f);
            if (v != 0.0f) {
                int pos = base + __popcll(m & ((1ull << lane) - 1ull));
                if (pos < K_CAP) erow[pos] = it * 256 + lane * 4 + k;
            }
            base += __popcll(m);
        }
    }
    if (lane == 0) {
        cnt[row]  = base < K_CAP ? base : K_CAP;
        dinv[row] = rsqrtf((float)base + 1.0f);  // self-loop adds 1
    }
}

// ---------------------------------------------------------------------------
// Kernel 2: h = x @ proj_w + proj_b, fused with layer-0 LN+ReLU -> z0.
// Block = 256 = 4 rows x 64 cols (one wave per row). W staged in LDS.
// ---------------------------------------------------------------------------
__global__ __launch_bounds__(256) void k_proj_ln(const float* __restrict__ x,
                                                 const float* __restrict__ w,
                                                 const float* __restrict__ b,
                                                 const float* __restrict__ g0,
                                                 const float* __restrict__ b0,
                                                 float* __restrict__ h,
                                                 float* __restrict__ z0) {
    __shared__ float sw[IN * HID];
    __shared__ float sx[4][IN];
    int tx = threadIdx.x;
    for (int i = tx; i < IN * HID; i += 256) sw[i] = w[i];
    int row0 = blockIdx.x * 4;
    if (tx < 128) {
        float4 v = *(const float4*)(x + (size_t)(row0 + (tx >> 5)) * IN + (tx & 31) * 4);
        *(float4*)&sx[tx >> 5][(tx & 31) * 4] = v;
    }
    __syncthreads();
    int c = tx & 63, r = tx >> 6;
    float acc = b[c];
#pragma unroll
    for (int k = 0; k < IN; k += 4) {
        float4 xa = *(const float4*)&sx[r][k];
        acc += xa.x * sw[(k + 0) * HID + c];
        acc += xa.y * sw[(k + 1) * HID + c];
        acc += xa.z * sw[(k + 2) * HID + c];
        acc += xa.w * sw[(k + 3) * HID + c];
    }
    size_t idx = (size_t)(row0 + r) * HID + c;
    h[idx] = acc;
    float sum = acc;
    for (int o = 32; o >= 1; o >>= 1) sum += __shfl_xor(sum, o);
    float mu = sum * (1.0f / 64.0f);
    float d  = acc - mu;
    float vs = d * d;
    for (int o = 32; o >= 1; o >>= 1) vs += __shfl_xor(vs, o);
    float rr = rsqrtf(vs * (1.0f / 64.0f) + EPS);
    float zz = d * rr * g0[c] + b0[c];
    z0[idx] = zz > 0.0f ? zz : 0.0f;
}

// ---------------------------------------------------------------------------
// Kernel 3 (per layer, fully fused):
//   s     = (1-ALPHA) * (A_hat @ z_in) + ALPHA * z_in
//   h    += (1-beta)*s + beta*(s @ conv_w)
//   z_out = relu(LN(h))   OR (last layer)   out = h @ head_w + head_b
//
// Gather is 4-way neighbor-parallel: lane = 16*q + p; group q handles
// neighbors t = q, q+4, ...; each lane loads float4 of features [4p,4p+4).
// CRITICAL: the loop bound is padded to a wave-UNIFORM ntot so all 64 lanes
// stay active at every __shfl (ds_bpermute from an EXEC-inactive lane is
// undefined -- this was round 3's correctness bug). Padding slots source
// lanes with myw==0, contributing exactly zero.
// ---------------------------------------------------------------------------
__global__ __launch_bounds__(256) void k_layer(
    float* __restrict__ h, const float* __restrict__ z_in,
    float* __restrict__ z_out,
    const int* __restrict__ ell, const int* __restrict__ cnt,
    const float* __restrict__ dinv, const float* __restrict__ w,
    const float* __restrict__ g_next, const float* __restrict__ b_next,
    float beta, int is_last,
    const float* __restrict__ head_w, const float* __restrict__ head_b,
    float* __restrict__ out) {
    __shared__ float sw[HID * HID];
    __shared__ float ss[4][HID];
    int tx = threadIdx.x;
    int lane = tx & 63, r = tx >> 6;
    int p = lane & 15, q = lane >> 4;
    int row = blockIdx.x * 4 + r;
    for (int i = tx; i < HID * HID; i += 256) sw[i] = w[i];

    int jbase = row & ~(N - 1);  // batch slab base
    const int* erow = ell + (size_t)row * K_CAP;
    int n = cnt[row];
    float di = dinv[row];
    float4 zi4 = *(const float4*)(z_in + (size_t)row * HID + 4 * p);
    int   myidx = 0;
    float myw   = 0.0f;
    if (lane < n) { myidx = erow[lane]; myw = dinv[jbase + myidx]; }

    float4 acc = make_float4(0.0f, 0.0f, 0.0f, 0.0f);
    int nmain = n < 64 ? n : 64;
    int ntot  = (nmain + 3) & ~3;  // wave-uniform trip count: ntot/4 per group
    for (int t = q; t < ntot; t += 4) {
        int   j  = jbase + __shfl(myidx, t);   // all 64 lanes active here
        float wj = __shfl(myw, t);             // t >= n sources myw == 0
        float4 zj = *(const float4*)(z_in + (size_t)j * HID + 4 * p);
        acc.x += wj * zj.x; acc.y += wj * zj.y;
        acc.z += wj * zj.z; acc.w += wj * zj.w;
    }
    for (int t = 64 + q; t < n; t += 4) {  // rare tail (deg > 64), no shfl
        int   j  = jbase + erow[t];
        float wj = dinv[j];
        float4 zj = *(const float4*)(z_in + (size_t)j * HID + 4 * p);
        acc.x += wj * zj.x; acc.y += wj * zj.y;
        acc.z += wj * zj.z; acc.w += wj * zj.w;
    }
    // merge the 4 neighbor groups (lanes differing in bits 4 and 5)
    acc.x += __shfl_xor(acc.x, 16); acc.y += __shfl_xor(acc.y, 16);
    acc.z += __shfl_xor(acc.z, 16); acc.w += __shfl_xor(acc.w, 16);
    acc.x += __shfl_xor(acc.x, 32); acc.y += __shfl_xor(acc.y, 32);
    acc.z += __shfl_xor(acc.z, 32); acc.w += __shfl_xor(acc.w, 32);

    float4 s4;
    s4.x = (1.0f - ALPHA) * di * (acc.x + di * zi4.x) + ALPHA * zi4.x;
    s4.y = (1.0f - ALPHA) * di * (acc.y + di * zi4.y) + ALPHA * zi4.y;
    s4.z = (1.0f - ALPHA) * di * (acc.z + di * zi4.z) + ALPHA * zi4.z;
    s4.w = (1.0f - ALPHA) * di * (acc.w + di * zi4.w) + ALPHA * zi4.w;
    if (q == 0) *(float4*)&ss[r][4 * p] = s4;
    __syncthreads();

    float mv = 0.0f;
#pragma unroll
    for (int k = 0; k < HID; k += 4) {
        float4 sk = *(const float4*)&ss[r][k];  // wave-uniform -> LDS broadcast
        mv += sk.x * sw[(k + 0) * HID + lane];
        mv += sk.y * sw[(k + 1) * HID + lane];
        mv += sk.z * sw[(k + 2) * HID + lane];
        mv += sk.w * sw[(k + 3) * HID + lane];
    }
    float s_c = ss[r][lane];
    size_t idx = (size_t)row * HID + lane;
    float hn = h[idx] + (1.0f - beta) * s_c + beta * mv;
    if (!is_last) {
        h[idx] = hn;
        float sum = hn;
        for (int o = 32; o >= 1; o >>= 1) sum += __shfl_xor(sum, o);
        float mu = sum * (1.0f / 64.0f);
        float d  = hn - mu;
        float vs = d * d;
        for (int o = 32; o >= 1; o >>= 1) vs += __shfl_xor(vs, o);
        float rr = rsqrtf(vs * (1.0f / 64.0f) + EPS);
        float zz = d * rr * g_next[lane] + b_next[lane];
        z_out[idx] = zz > 0.0f ? zz : 0.0f;
    } else {
        float v = hn * head_w[lane];
        for (int o = 32; o >= 1; o >>= 1) v += __shfl_xor(v, o);
        if (lane == 0) out[row] = v + head_b[0];
    }
}

extern "C" void kernel_launch(void* const* d_in, const int* in_sizes, int n_in,
                              void* d_out, int out_size, void* d_ws, size_t ws_size,
                              hipStream_t stream) {
    const float* x      = (const float*)d_in[0];
    const float* adj    = (const float*)d_in[1];
    const float* proj_w = (const float*)d_in[2];
    const float* proj_b = (const float*)d_in[3];
    const float* ln_g   = (const float*)d_in[4];
    const float* ln_b   = (const float*)d_in[5];
    const float* conv_w = (const float*)d_in[6];
    const float* head_w = (const float*)d_in[7];
    const float* head_b = (const float*)d_in[8];
    float* out = (float*)d_out;

    float* h    = (float*)d_ws;                  // ROWS*HID
    float* za   = h + (size_t)ROWS * HID;        // ROWS*HID
    float* zb   = za + (size_t)ROWS * HID;       // ROWS*HID
    float* dinv = zb + (size_t)ROWS * HID;       // ROWS
    int*   cnt  = (int*)(dinv + ROWS);           // ROWS
    int*   ell  = cnt + ROWS;                    // ROWS*K_CAP

    dim3 blk(256), grd(ROWS / 4);

    k_build<<<grd, blk, 0, stream>>>(adj, ell, cnt, dinv);
    k_proj_ln<<<grd, blk, 0, stream>>>(x, proj_w, proj_b, ln_g, ln_b, h, za);

    float* zin = za;
    float* zout = zb;
    for (int i = 0; i < 4; i++) {
        float beta = (float)log(1.0 / (double)(i + 1) + 1.0);
        int last = (i == 3);
        int gi = (i + 1) < 3 ? (i + 1) : 3;
        k_layer<<<grd, blk, 0, stream>>>(h, zin, zout, ell, cnt, dinv,
                                         conv_w + (size_t)i * HID * HID,
                                         ln_g + gi * HID, ln_b + gi * HID,
                                         beta, last, head_w, head_b, out);
        float* t = zin; zin = zout; zout = t;
    }
}

// Round 6
// 404.851 us; speedup vs baseline: 2.1329x; 1.1347x over previous
//
#include <hip/hip_runtime.h>
#include <math.h>

#define BS 32
#define N 2048
#define ROWS (BS * N)
#define IN 128
#define HID 64
#define K_CAP 80
#define EPS 1e-5f
#define ALPHA 0.1f

typedef float fx4 __attribute__((ext_vector_type(4)));  // nontemporal-compatible

// ---------------------------------------------------------------------------
// Kernel 1: build ELL adjacency + dinv = rsqrt(deg+1).
// One wave per row; nontemporal ext-vector float4 loads (adj is read exactly
// once -> don't pollute L2/L3). Reads 536 MB: the HBM floor of the problem.
// ---------------------------------------------------------------------------
__global__ __launch_bounds__(256) void k_build(const float* __restrict__ adj,
                                               int* __restrict__ ell,
                                               int* __restrict__ cnt,
                                               float* __restrict__ dinv) {
    int lane = threadIdx.x & 63;
    int row  = blockIdx.x * 4 + (threadIdx.x >> 6);
    const fx4* arow = (const fx4*)(adj + (size_t)row * N);
    int* erow = ell + (size_t)row * K_CAP;
    int base = 0;
#pragma unroll
    for (int it = 0; it < N / 256; it++) {
        fx4 f = __builtin_nontemporal_load(&arow[it * 64 + lane]);
#pragma unroll
        for (int k = 0; k < 4; k++) {
            float v = f[k];
            unsigned long long m = __ballot(v != 0.0f);
            if (v != 0.0f) {
                int pos = base + __popcll(m & ((1ull << lane) - 1ull));
                if (pos < K_CAP) erow[pos] = it * 256 + lane * 4 + k;
            }
            base += __popcll(m);
        }
    }
    if (lane == 0) {
        cnt[row]  = base < K_CAP ? base : K_CAP;
        dinv[row] = rsqrtf((float)base + 1.0f);  // self-loop adds 1
    }
}

// ---------------------------------------------------------------------------
// Kernel 2: h = x @ proj_w + proj_b, fused with layer-0 LN+ReLU -> z0.
// ---------------------------------------------------------------------------
__global__ __launch_bounds__(256) void k_proj_ln(const float* __restrict__ x,
                                                 const float* __restrict__ w,
                                                 const float* __restrict__ b,
                                                 const float* __restrict__ g0,
                                                 const float* __restrict__ b0,
                                                 float* __restrict__ h,
                                                 float* __restrict__ z0) {
    __shared__ float sw[IN * HID];
    __shared__ float sx[4][IN];
    int tx = threadIdx.x;
    for (int i = tx; i < IN * HID; i += 256) sw[i] = w[i];
    int row0 = blockIdx.x * 4;
    if (tx < 128) {
        float4 v = *(const float4*)(x + (size_t)(row0 + (tx >> 5)) * IN + (tx & 31) * 4);
        *(float4*)&sx[tx >> 5][(tx & 31) * 4] = v;
    }
    __syncthreads();
    int c = tx & 63, r = tx >> 6;
    float acc = b[c];
#pragma unroll
    for (int k = 0; k < IN; k += 4) {
        float4 xa = *(const float4*)&sx[r][k];
        acc += xa.x * sw[(k + 0) * HID + c];
        acc += xa.y * sw[(k + 1) * HID + c];
        acc += xa.z * sw[(k + 2) * HID + c];
        acc += xa.w * sw[(k + 3) * HID + c];
    }
    size_t idx = (size_t)(row0 + r) * HID + c;
    h[idx] = acc;
    float sum = acc;
    for (int o = 32; o >= 1; o >>= 1) sum += __shfl_xor(sum, o);
    float mu = sum * (1.0f / 64.0f);
    float d  = acc - mu;
    float vs = d * d;
    for (int o = 32; o >= 1; o >>= 1) vs += __shfl_xor(vs, o);
    float rr = rsqrtf(vs * (1.0f / 64.0f) + EPS);
    float zz = d * rr * g0[c] + b0[c];
    z0[idx] = zz > 0.0f ? zz : 0.0f;
}

// ---------------------------------------------------------------------------
// Kernel 3 (per layer, fully fused). 16 rows per block (4 waves x 4 rows):
//  - XCD-aware swizzle: 4096 blocks, XCD k gets contiguous chunk -> batches
//    4k..4k+3 (z slab 2 MB) stay in that XCD's 4 MB L2 across the gather AND
//    across layers (same swizzle every layer).
//  - conv_w LDS stage amortized over 16 rows.
//  - h is streaming (read/write once) -> nontemporal, keeps L2 for z.
//  - gather: 4-way neighbor-parallel, float4 features, wave-uniform trip
//    count (all 64 lanes active at every __shfl -- round-3 lesson).
// ---------------------------------------------------------------------------
__global__ __launch_bounds__(256) void k_layer(
    float* __restrict__ h, const float* __restrict__ z_in,
    float* __restrict__ z_out,
    const int* __restrict__ ell, const int* __restrict__ cnt,
    const float* __restrict__ dinv, const float* __restrict__ w,
    const float* __restrict__ g_next, const float* __restrict__ b_next,
    float beta, int is_last,
    const float* __restrict__ head_w, const float* __restrict__ head_b,
    float* __restrict__ out) {
    __shared__ float sw[HID * HID];
    __shared__ float ss[16][HID];
    int tx = threadIdx.x;
    int lane = tx & 63, wid = tx >> 6;
    int p = lane & 15, q = lane >> 4;

    // XCD-aware bijective swizzle (gridDim.x = 4096, divisible by 8)
    int bid = blockIdx.x;
    int swz = (bid & 7) * (int)(gridDim.x >> 3) + (bid >> 3);
    int row0 = swz * 16 + wid * 4;           // this wave's 4 rows
    int jbase = row0 & ~(N - 1);             // batch slab base (16 | 2048)

    for (int i = tx; i < HID * HID; i += 256) sw[i] = w[i];

    // ---- per-row state preload (independent loads, deep MLP) ----
    int   nn[4];
    float di[4];
    int   myidx[4];
    float myw[4];
    float4 zi4[4];
#pragma unroll
    for (int rr = 0; rr < 4; rr++) {
        int row = row0 + rr;
        nn[rr] = cnt[row];
        di[rr] = dinv[row];
        zi4[rr] = *(const float4*)(z_in + (size_t)row * HID + 4 * p);
        myidx[rr] = 0; myw[rr] = 0.0f;
        if (lane < nn[rr]) {
            myidx[rr] = ell[(size_t)row * K_CAP + lane];
            myw[rr]   = dinv[jbase + myidx[rr]];
        }
    }

    // ---- gather + s for each of the 4 rows ----
#pragma unroll
    for (int rr = 0; rr < 4; rr++) {
        float4 acc = make_float4(0.0f, 0.0f, 0.0f, 0.0f);
        int nmain = nn[rr] < 64 ? nn[rr] : 64;
        int ntot  = (nmain + 3) & ~3;        // wave-uniform trip count
        for (int t = q; t < ntot; t += 4) {
            int   j  = jbase + __shfl(myidx[rr], t);  // all 64 lanes active
            float wj = __shfl(myw[rr], t);            // t >= n -> wj == 0
            float4 zj = *(const float4*)(z_in + (size_t)j * HID + 4 * p);
            acc.x += wj * zj.x; acc.y += wj * zj.y;
            acc.z += wj * zj.z; acc.w += wj * zj.w;
        }
        for (int t = 64 + q; t < nn[rr]; t += 4) {    // rare deg>64 tail
            int   j  = jbase + ell[(size_t)(row0 + rr) * K_CAP + t];
            float wj = dinv[j];
            float4 zj = *(const float4*)(z_in + (size_t)j * HID + 4 * p);
            acc.x += wj * zj.x; acc.y += wj * zj.y;
            acc.z += wj * zj.z; acc.w += wj * zj.w;
        }
        acc.x += __shfl_xor(acc.x, 16); acc.y += __shfl_xor(acc.y, 16);
        acc.z += __shfl_xor(acc.z, 16); acc.w += __shfl_xor(acc.w, 16);
        acc.x += __shfl_xor(acc.x, 32); acc.y += __shfl_xor(acc.y, 32);
        acc.z += __shfl_xor(acc.z, 32); acc.w += __shfl_xor(acc.w, 32);
        float dd = di[rr];
        float4 s4;
        s4.x = (1.0f - ALPHA) * dd * (acc.x + dd * zi4[rr].x) + ALPHA * zi4[rr].x;
        s4.y = (1.0f - ALPHA) * dd * (acc.y + dd * zi4[rr].y) + ALPHA * zi4[rr].y;
        s4.z = (1.0f - ALPHA) * dd * (acc.z + dd * zi4[rr].z) + ALPHA * zi4[rr].z;
        s4.w = (1.0f - ALPHA) * dd * (acc.w + dd * zi4[rr].w) + ALPHA * zi4[rr].w;
        if (q == 0) *(float4*)&ss[wid * 4 + rr][4 * p] = s4;
    }
    __syncthreads();  // covers the block-wide sw stage (ss is wave-private)

    // ---- matvec + residual + LN/head for each of the 4 rows ----
#pragma unroll
    for (int rr = 0; rr < 4; rr++) {
        int row = row0 + rr;
        float mv = 0.0f;
#pragma unroll
        for (int k = 0; k < HID; k += 4) {
            float4 sk = *(const float4*)&ss[wid * 4 + rr][k];  // LDS broadcast
            mv += sk.x * sw[(k + 0) * HID + lane];
            mv += sk.y * sw[(k + 1) * HID + lane];
            mv += sk.z * sw[(k + 2) * HID + lane];
            mv += sk.w * sw[(k + 3) * HID + lane];
        }
        float s_c = ss[wid * 4 + rr][lane];
        size_t idx = (size_t)row * HID + lane;
        float hn = __builtin_nontemporal_load(h + idx) +
                   (1.0f - beta) * s_c + beta * mv;
        if (!is_last) {
            __builtin_nontemporal_store(hn, h + idx);
            float sum = hn;
            for (int o = 32; o >= 1; o >>= 1) sum += __shfl_xor(sum, o);
            float mu = sum * (1.0f / 64.0f);
            float d  = hn - mu;
            float vs = d * d;
            for (int o = 32; o >= 1; o >>= 1) vs += __shfl_xor(vs, o);
            float rv = rsqrtf(vs * (1.0f / 64.0f) + EPS);
            float zz = d * rv * g_next[lane] + b_next[lane];
            z_out[idx] = zz > 0.0f ? zz : 0.0f;  // normal store: next layer's gather wants it in L2
        } else {
            float v = hn * head_w[lane];
            for (int o = 32; o >= 1; o >>= 1) v += __shfl_xor(v, o);
            if (lane == 0) out[row] = v + head_b[0];
        }
    }
}

extern "C" void kernel_launch(void* const* d_in, const int* in_sizes, int n_in,
                              void* d_out, int out_size, void* d_ws, size_t ws_size,
                              hipStream_t stream) {
    const float* x      = (const float*)d_in[0];
    const float* adj    = (const float*)d_in[1];
    const float* proj_w = (const float*)d_in[2];
    const float* proj_b = (const float*)d_in[3];
    const float* ln_g   = (const float*)d_in[4];
    const float* ln_b   = (const float*)d_in[5];
    const float* conv_w = (const float*)d_in[6];
    const float* head_w = (const float*)d_in[7];
    const float* head_b = (const float*)d_in[8];
    float* out = (float*)d_out;

    float* h    = (float*)d_ws;                  // ROWS*HID
    float* za   = h + (size_t)ROWS * HID;        // ROWS*HID
    float* zb   = za + (size_t)ROWS * HID;       // ROWS*HID
    float* dinv = zb + (size_t)ROWS * HID;       // ROWS
    int*   cnt  = (int*)(dinv + ROWS);           // ROWS
    int*   ell  = cnt + ROWS;                    // ROWS*K_CAP

    dim3 blk(256);

    k_build<<<dim3(ROWS / 4), blk, 0, stream>>>(adj, ell, cnt, dinv);
    k_proj_ln<<<dim3(ROWS / 4), blk, 0, stream>>>(x, proj_w, proj_b, ln_g, ln_b, h, za);

    float* zin = za;
    float* zout = zb;
    for (int i = 0; i < 4; i++) {
        float beta = (float)log(1.0 / (double)(i + 1) + 1.0);
        int last = (i == 3);
        int gi = (i + 1) < 3 ? (i + 1) : 3;
        k_layer<<<dim3(ROWS / 16), blk, 0, stream>>>(h, zin, zout, ell, cnt, dinv,
                                                     conv_w + (size_t)i * HID * HID,
                                                     ln_g + gi * HID, ln_b + gi * HID,
                                                     beta, last, head_w, head_b, out);
        float* t = zin; zin = zout; zout = t;
    }
}